// Round 3
// baseline (21686.111 us; speedup 1.0000x reference)
//
#include <hip/hip_runtime.h>
#include <cstdint>
#include <cstddef>

// Problem constants (T, B, I, H, L) = (2048, 64, 256, 256, 2)
#define T_STEPS 2048
#define BB 64
#define II 256
#define HH 256
#define GG 1024
#define RING 64     // h ring depth (steps); power of 2
#define NSL 16      // weight slices (blocks) per layer
#define DPS 16      // h-dims per slice (NSL*DPS == HH)

typedef _Float16 half8_t __attribute__((ext_vector_type(8)));
typedef float    f32x4_t __attribute__((ext_vector_type(4)));
typedef unsigned long long u64;

static __device__ __forceinline__ float sigm(float x) {
    return 1.0f / (1.0f + __expf(-x));
}
static __device__ __forceinline__ float tanhfast(float x) {
    float e = __expf(2.0f * x);
    return 1.0f - 2.0f / (e + 1.0f);
}

// relaxed agent-scope atomics: cross-XCD coherent (MALL) with NO buffer_inv/wbl2
// (round-1 lesson). Ordering comes from __syncthreads (vmcnt(0) drain) + flag.
static __device__ __forceinline__ u64 aload64(const u64* p) {
    return __hip_atomic_load((u64*)p, __ATOMIC_RELAXED, __HIP_MEMORY_SCOPE_AGENT);
}
static __device__ __forceinline__ void astore64(u64* p, u64 v) {
    __hip_atomic_store(p, v, __ATOMIC_RELAXED, __HIP_MEMORY_SCOPE_AGENT);
}
static __device__ __forceinline__ int aloadi(const int* p) {
    return __hip_atomic_load((int*)p, __ATOMIC_RELAXED, __HIP_MEMORY_SCOPE_AGENT);
}
static __device__ __forceinline__ void astorei(int* p, int v) {
    __hip_atomic_store(p, v, __ATOMIC_RELAXED, __HIP_MEMORY_SCOPE_AGENT);
}
#define CFENCE asm volatile("" ::: "memory")

union H8 { struct { u64 lo, hi; } u; half8_t v; };

// ---------------- prep kernels (tiny) ----------------
__global__ void k_f32_to_f16(const float* __restrict__ in, _Float16* __restrict__ out, int n) {
    int i = (blockIdx.x * blockDim.x + threadIdx.x) * 4;
    if (i >= n) return;
    float4 v = *(const float4*)(in + i);
    half8_t h;
    h[0] = (_Float16)v.x; h[1] = (_Float16)v.y; h[2] = (_Float16)v.z; h[3] = (_Float16)v.w;
    *(_Float16*)(out + i) = h[0];
    out[i + 1] = h[1]; out[i + 2] = h[2]; out[i + 3] = h[3];
}

__global__ void k_bias_sum(const float* __restrict__ a, const float* __restrict__ b,
                           float* __restrict__ o) {
    int i = threadIdx.x;  // 1024 threads, 1 block
    o[i] = a[i] + b[i];
}

// zero hR slot RING-1 (both layers) + progress flags
__global__ void k_init(_Float16* __restrict__ hR, int* __restrict__ prog) {
    int L = blockIdx.x >> 3, part = blockIdx.x & 7;
    size_t off = ((size_t)L * RING + (RING - 1)) * (BB * HH) + (size_t)part * 2048
               + (size_t)threadIdx.x * 8;
    ((u64*)(hR + off))[0] = 0ull;
    ((u64*)(hR + off))[1] = 0ull;
    if (blockIdx.x == 0 && threadIdx.x < 64) prog[threadIdx.x] = 0;
}

// ---------------- fused 2-layer sliced-MFMA pipeline ----------------
// 32 blocks = 2 layers x 16 slices; 256 threads (4 waves). Block (L, sl) owns
// h-dims [sl*16, sl*16+16) -> 64 gate rows; W_ih+W_hh slices = 64 KB = 32
// MFMA B-frags/thread (128 dw), loaded ONCE (truly resident -- the round-2
// lesson: 512 KB/CU can never be resident; 64 KB can).
// Per step: gates(64b x 64rows) = [x|h0](64x256) @ Wih_sl^T + h[t-1](64x256) @ Whh_sl^T
// via mfma_f32_16x16x32_f16 (layout conventions from the verified k_gemm_xg).
// h[t] pieces exchanged through MALL rings + per-slice progress flags.
//   hR[2][RING][B][H] : post-reset h (recurrence input, both layers)
//   hX[RING][B][H]    : pre-reset h_b of layer 0 (layer 1's input; differs from
//                       hR on reset steps -- reference semantics)
__global__ __launch_bounds__(256, 1)
__attribute__((amdgpu_waves_per_eu(1, 1)))
void k_pipe(const _Float16* __restrict__ xh,    // (T,B,I) f16 (preconverted)
            const _Float16* __restrict__ w0ih,  // (1024,256) f16 row-major
            const _Float16* __restrict__ w0hh,
            const _Float16* __restrict__ w1ih,
            const _Float16* __restrict__ w1hh,
            const float* __restrict__ bsum0,    // (1024) b_ih+b_hh
            const float* __restrict__ bsum1,
            const float* __restrict__ mask,     // (T,B)
            const float* __restrict__ reset,    // (T,B)
            _Float16* __restrict__ hR,          // [2][RING][B][H]
            _Float16* __restrict__ hX,          // [RING][B][H]
            float* __restrict__ out,            // (T,B,H)
            float* __restrict__ hn,             // (2,B,H)
            float* __restrict__ cn,             // (2,B,H)
            int* __restrict__ prog)             // [2][16] (+pad)
{
    __shared__ __align__(16) float acts[4 * DPS * BB];     // 16 KB, [g][j][b], XOR-swz
    __shared__ __align__(16) _Float16 hsR[BB * DPS];       // 2 KB, [b][j]
    __shared__ __align__(16) _Float16 hsX[BB * DPS];       // 2 KB
    __shared__ __align__(16) float osF[BB * DPS];          // 4 KB f32 out stage (L1)

    const int L   = blockIdx.x >> 4;
    const int sl  = blockIdx.x & 15;
    const int tid = threadIdx.x;
    const int lane = tid & 63, l15 = lane & 15, q = lane >> 4;
    const int wave = tid >> 6;
    const int waveN = wave & 1;          // gate pair: 0 -> {i,g}, 1 -> {f,o}
    const int waveM = wave >> 1;         // batch half: mi = 2*waveM + mm

    const _Float16* Wih = L ? w1ih : w0ih;
    const _Float16* Whh = L ? w1hh : w0hh;
    const float* bsum = L ? bsum1 : bsum0;

    // ---- resident B-frags (loaded once; 32 frags = 128 dw/thread) ----
    // frag(p, kj): lane reads W[grow(p)][kj*32 + q*8 .. +8], grow(p) = gate row
    const int grow0 = waveN * 256 + sl * DPS + l15;         // gate waveN   (i or f)
    const int grow1 = (waveN + 2) * 256 + sl * DPS + l15;   // gate waveN+2 (g or o)
    half8_t bih[2][8], bhh[2][8];
#pragma unroll
    for (int kj = 0; kj < 8; ++kj) {
        bih[0][kj] = *(const half8_t*)(Wih + (size_t)grow0 * HH + kj * 32 + q * 8);
        bih[1][kj] = *(const half8_t*)(Wih + (size_t)grow1 * HH + kj * 32 + q * 8);
        bhh[0][kj] = *(const half8_t*)(Whh + (size_t)grow0 * HH + kj * 32 + q * 8);
        bhh[1][kj] = *(const half8_t*)(Whh + (size_t)grow1 * HH + kj * 32 + q * 8);
    }
    const float bsv0 = bsum[grow0], bsv1 = bsum[grow1];

    // finisher identity: 4 cells = (dim jf, batches bf..bf+3)
    const int jf = tid & 15, bf = (tid >> 4) * 4;
    float cS[4] = {0.f, 0.f, 0.f, 0.f};
    float hS[4] = {0.f, 0.f, 0.f, 0.f};

    // rows (batches) this wave's A-frags cover
    const int rowA0 = (2 * waveM + 0) * 16 + l15;
    const int rowA1 = (2 * waveM + 1) * 16 + l15;

    int* myf = prog + L * NSL + sl;

    for (int t = 0; t < T_STEPS; ++t) {
        // ---- spin (wave 0 only): peers' h[t-1], source hX[t] (L1), consumer lag (L0)
        if (wave == 0) {
            const int* fp = nullptr; int tgt = -2147483647;
            if (lane < 16) { fp = prog + L * NSL + lane; tgt = t; }
            else if (lane < 32) {
                fp = L ? (prog + (lane - 16)) : (prog + NSL + (lane - 16));
                tgt = L ? (t + 1) : (t - (RING - 4));
            }
            int v = 0x7fffffff;
            if (fp) v = aloadi(fp);
            while (!__all(v >= tgt)) {
                __builtin_amdgcn_s_sleep(1);
                if (fp) v = aloadi(fp);
            }
            CFENCE;
        }
        __syncthreads();  // B1: flags satisfied for everyone

        // ---- issue h[t-1] A-frags (agent-coherent 8B loads; land during x phase)
        H8 hA[2][8];
        const _Float16* hsrc = hR + ((size_t)L * RING + ((t + RING - 1) & (RING - 1))) * (BB * HH);
#pragma unroll
        for (int kj = 0; kj < 8; ++kj) {
            const u64* p0 = (const u64*)(hsrc + (size_t)rowA0 * HH + kj * 32 + q * 8);
            const u64* p1 = (const u64*)(hsrc + (size_t)rowA1 * HH + kj * 32 + q * 8);
            hA[0][kj].u.lo = aload64(p0); hA[0][kj].u.hi = aload64(p0 + 1);
            hA[1][kj].u.lo = aload64(p1); hA[1][kj].u.hi = aload64(p1 + 1);
        }

        // ---- issue x A-frags (L0: static f16 input; L1: hX ring, agent loads)
        half8_t xa[2][8];
        if (L == 0) {
            const _Float16* xs = xh + (size_t)t * (BB * HH);
#pragma unroll
            for (int kj = 0; kj < 8; ++kj) {
                xa[0][kj] = *(const half8_t*)(xs + (size_t)rowA0 * HH + kj * 32 + q * 8);
                xa[1][kj] = *(const half8_t*)(xs + (size_t)rowA1 * HH + kj * 32 + q * 8);
            }
        } else {
            const _Float16* xs = hX + (size_t)(t & (RING - 1)) * (BB * HH);
#pragma unroll
            for (int kj = 0; kj < 8; ++kj) {
                H8 a, b;
                const u64* p0 = (const u64*)(xs + (size_t)rowA0 * HH + kj * 32 + q * 8);
                const u64* p1 = (const u64*)(xs + (size_t)rowA1 * HH + kj * 32 + q * 8);
                a.u.lo = aload64(p0); a.u.hi = aload64(p0 + 1);
                b.u.lo = aload64(p1); b.u.hi = aload64(p1 + 1);
                xa[0][kj] = a.v; xa[1][kj] = b.v;
            }
        }

        // mask/reset for finisher cells (hidden under matvec)
        const float4 mv = *(const float4*)(mask + (size_t)t * BB + bf);
        const float4 rv = *(const float4*)(reset + (size_t)t * BB + bf);

        // ---- MFMA: acc init = bias; ih then hh (C/D layout per verified k_gemm_xg)
        f32x4_t acc[2][2];
        acc[0][0] = f32x4_t{bsv0, bsv0, bsv0, bsv0};
        acc[0][1] = f32x4_t{bsv1, bsv1, bsv1, bsv1};
        acc[1][0] = f32x4_t{bsv0, bsv0, bsv0, bsv0};
        acc[1][1] = f32x4_t{bsv1, bsv1, bsv1, bsv1};
#pragma unroll
        for (int kj = 0; kj < 8; ++kj) {
            acc[0][0] = __builtin_amdgcn_mfma_f32_16x16x32_f16(xa[0][kj], bih[0][kj], acc[0][0], 0, 0, 0);
            acc[0][1] = __builtin_amdgcn_mfma_f32_16x16x32_f16(xa[0][kj], bih[1][kj], acc[0][1], 0, 0, 0);
            acc[1][0] = __builtin_amdgcn_mfma_f32_16x16x32_f16(xa[1][kj], bih[0][kj], acc[1][0], 0, 0, 0);
            acc[1][1] = __builtin_amdgcn_mfma_f32_16x16x32_f16(xa[1][kj], bih[1][kj], acc[1][1], 0, 0, 0);
        }
#pragma unroll
        for (int kj = 0; kj < 8; ++kj) {
            acc[0][0] = __builtin_amdgcn_mfma_f32_16x16x32_f16(hA[0][kj].v, bhh[0][kj], acc[0][0], 0, 0, 0);
            acc[0][1] = __builtin_amdgcn_mfma_f32_16x16x32_f16(hA[0][kj].v, bhh[1][kj], acc[0][1], 0, 0, 0);
            acc[1][0] = __builtin_amdgcn_mfma_f32_16x16x32_f16(hA[1][kj].v, bhh[0][kj], acc[1][0], 0, 0, 0);
            acc[1][1] = __builtin_amdgcn_mfma_f32_16x16x32_f16(hA[1][kj].v, bhh[1][kj], acc[1][1], 0, 0, 0);
        }

        // ---- activations -> LDS [g][j][b] (XOR-swizzled, b128 writes)
        // cell (mm,p,r): gate g = waveN+2p, j = l15, b = (2*waveM+mm)*16 + q*4 + r
#pragma unroll
        for (int mm = 0; mm < 2; ++mm) {
#pragma unroll
            for (int p = 0; p < 2; ++p) {
                const int g = waveN + 2 * p;
                f32x4_t av;
#pragma unroll
                for (int r = 0; r < 4; ++r) {
                    float s = acc[mm][p][r];
                    av[r] = (g == 2) ? tanhfast(s) : sigm(s);
                }
                unsigned dwoff = (unsigned)(((g * DPS + l15) * BB) + (2 * waveM + mm) * 16 + q * 4);
                unsigned byteoff = (dwoff * 4u) ^ ((unsigned)(l15 & 7) << 4);
                *(f32x4_t*)((char*)acts + byteoff) = av;
            }
        }
        __syncthreads();  // B2: acts visible

        // ---- finisher: 4 cells (jf, bf..bf+3)
        {
            f32x4_t gi, gf_, gg, go;
            {
                unsigned swz = ((unsigned)(jf & 7) << 4);
                gi  = *(const f32x4_t*)((const char*)acts + ((((0 * DPS + jf) * BB + bf) * 4u) ^ swz));
                gf_ = *(const f32x4_t*)((const char*)acts + ((((1 * DPS + jf) * BB + bf) * 4u) ^ swz));
                gg  = *(const f32x4_t*)((const char*)acts + ((((2 * DPS + jf) * BB + bf) * 4u) ^ swz));
                go  = *(const f32x4_t*)((const char*)acts + ((((3 * DPS + jf) * BB + bf) * 4u) ^ swz));
            }
            const float mm4[4] = {mv.x, mv.y, mv.z, mv.w};
            const float rr4[4] = {rv.x, rv.y, rv.z, rv.w};
#pragma unroll
            for (int e = 0; e < 4; ++e) {
                float cnew = gf_[e] * cS[e] + gi[e] * gg[e];
                float hnew = go[e] * tanhfast(cnew);
                float m = mm4[e], r = rr4[e];
                float hb = hnew * m + hS[e] * (1.f - m);
                float cb = cnew * m + cS[e] * (1.f - m);
                hS[e] = hb * (1.f - r);
                cS[e] = cb * (1.f - r);
                hsR[(bf + e) * DPS + jf] = (_Float16)hS[e];
                if (L == 0) hsX[(bf + e) * DPS + jf] = (_Float16)hb;
                else        osF[(bf + e) * DPS + jf] = hb;
            }
        }
        __syncthreads();  // B3: staging complete

        // ---- cooperative publish (agent-coherent 8B stores; coalesced)
        {
            const int b = tid >> 2, joff = (tid & 3) * 4;
            u64 vR = *(const u64*)(hsR + b * DPS + joff);
            _Float16* dR = hR + ((size_t)L * RING + (t & (RING - 1))) * (BB * HH)
                         + (size_t)b * HH + sl * DPS + joff;
            astore64((u64*)dR, vR);
            if (L == 0) {
                u64 vX = *(const u64*)(hsX + b * DPS + joff);
                _Float16* dX = hX + (size_t)(t & (RING - 1)) * (BB * HH)
                             + (size_t)b * HH + sl * DPS + joff;
                astore64((u64*)dX, vX);
            } else {
                const int bo = tid >> 2;  // out: 16B f32 per thread
                f32x4_t ov = *(const f32x4_t*)(osF + bo * DPS + joff);
                *(f32x4_t*)(out + ((size_t)t * BB + bo) * HH + sl * DPS + joff) = ov;
            }
        }
        __syncthreads();  // B4: drains vmcnt -> ring stores at MALL
        if (tid == 0) { astorei(myf, t + 1); CFENCE; }
    }

    // finals: hn/cn = post-reset carries (reference semantics)
#pragma unroll
    for (int e = 0; e < 4; ++e) {
        hn[((size_t)L * BB + bf + e) * HH + sl * DPS + jf] = hS[e];
        cn[((size_t)L * BB + bf + e) * HH + sl * DPS + jf] = cS[e];
    }
}

// ---------------- host ----------------
extern "C" void kernel_launch(void* const* d_in, const int* in_sizes, int n_in,
                              void* d_out, int out_size, void* d_ws, size_t ws_size,
                              hipStream_t stream) {
    (void)in_sizes; (void)n_in; (void)out_size; (void)ws_size;
    const float* input = (const float*)d_in[0];
    const float* maskp = (const float*)d_in[1];
    const float* resetp = (const float*)d_in[2];
    const float* Wih0 = (const float*)d_in[3];
    const float* Whh0 = (const float*)d_in[4];
    const float* bih0 = (const float*)d_in[5];
    const float* bhh0 = (const float*)d_in[6];
    const float* Wih1 = (const float*)d_in[7];
    const float* Whh1 = (const float*)d_in[8];
    const float* bih1 = (const float*)d_in[9];
    const float* bhh1 = (const float*)d_in[10];

    // workspace (~71 MiB)
    char* p = (char*)d_ws;
    _Float16* xh = (_Float16*)p;    p += (size_t)T_STEPS * BB * II * 2;   // 64 MiB
    _Float16* w0ihh = (_Float16*)p; p += (size_t)GG * II * 2;             // 512 KiB
    _Float16* w0hhh = (_Float16*)p; p += (size_t)GG * HH * 2;
    _Float16* w1ihh = (_Float16*)p; p += (size_t)GG * HH * 2;
    _Float16* w1hhh = (_Float16*)p; p += (size_t)GG * HH * 2;
    float* bsum0 = (float*)p;       p += GG * sizeof(float);
    float* bsum1 = (float*)p;       p += GG * sizeof(float);
    _Float16* hRr = (_Float16*)p;   p += (size_t)2 * RING * BB * HH * 2;  // 4 MiB
    _Float16* hXr = (_Float16*)p;   p += (size_t)RING * BB * HH * 2;      // 2 MiB
    int* prog = (int*)p;            p += 4096;

    float* out1 = (float*)d_out;                   // (T,B,H)
    float* hn = out1 + (size_t)T_STEPS * BB * HH;  // (2,B,H)
    float* cn = hn + 2 * (size_t)BB * HH;          // (2,B,H)

    // prep: f32->f16 conversions (x and all weights), bias sums, ring/flag init
    k_f32_to_f16<<<dim3((T_STEPS * BB * II) / 1024), 256, 0, stream>>>(input, xh, T_STEPS * BB * II);
    k_f32_to_f16<<<dim3((GG * II) / 1024), 256, 0, stream>>>(Wih0, w0ihh, GG * II);
    k_f32_to_f16<<<dim3((GG * HH) / 1024), 256, 0, stream>>>(Whh0, w0hhh, GG * HH);
    k_f32_to_f16<<<dim3((GG * HH) / 1024), 256, 0, stream>>>(Wih1, w1ihh, GG * HH);
    k_f32_to_f16<<<dim3((GG * HH) / 1024), 256, 0, stream>>>(Whh1, w1hhh, GG * HH);
    k_bias_sum<<<dim3(1), GG, 0, stream>>>(bih0, bhh0, bsum0);
    k_bias_sum<<<dim3(1), GG, 0, stream>>>(bih1, bhh1, bsum1);
    k_init<<<dim3(16), 256, 0, stream>>>(hRr, prog);  // flags MUST reset each launch

    const _Float16* a_xh = xh;
    const _Float16* a_w0i = w0ihh; const _Float16* a_w0h = w0hhh;
    const _Float16* a_w1i = w1ihh; const _Float16* a_w1h = w1hhh;
    const float* a_b0 = bsum0; const float* a_b1 = bsum1;
    const float* a_m = maskp; const float* a_r = resetp;
    _Float16* a_hR = hRr; _Float16* a_hX = hXr;
    float* a_out = out1; float* a_hn = hn; float* a_cn = cn; int* a_pr = prog;
    void* args[] = { &a_xh, &a_w0i, &a_w0h, &a_w1i, &a_w1h, &a_b0, &a_b1,
                     &a_m, &a_r, &a_hR, &a_hX, &a_out, &a_hn, &a_cn, &a_pr };

    // 32 blocks co-resident trivially; cooperative launch for guarantee,
    // plain fallback benign.
    hipError_t err = hipLaunchCooperativeKernel((const void*)k_pipe, dim3(2 * NSL),
                                                dim3(256), args, 0, stream);
    if (err != hipSuccess) {
        (void)hipGetLastError();
        k_pipe<<<dim3(2 * NSL), dim3(256), 0, stream>>>(
            a_xh, a_w0i, a_w0h, a_w1i, a_w1h, a_b0, a_b1,
            a_m, a_r, a_hR, a_hX, a_out, a_hn, a_cn, a_pr);
    }
}